// Round 12
// baseline (683.139 us; speedup 1.0000x reference)
//
#include <hip/hip_runtime.h>
#include <hip/hip_bf16.h>
#include <math.h>

#define BB 2048
#define KK 10
#define N1R 20480
#define Q2T 22528          // BB + N1R merged query rows
#define NNODES 100000

typedef short short4v __attribute__((ext_vector_type(4)));
typedef short short8 __attribute__((ext_vector_type(8)));
typedef float f32x4 __attribute__((ext_vector_type(4)));
typedef float f32x2 __attribute__((ext_vector_type(2)));

__device__ __forceinline__ float bf2f(short s) {
  union { unsigned u; float f; } x;
  x.u = ((unsigned)(unsigned short)s) << 16;
  return x.f;
}
__device__ __forceinline__ short f2bf(float f) {
  union { float f; unsigned u; } x;
  x.f = f;
  unsigned r = x.u + 0x7fffu + ((x.u >> 16) & 1u);
  return (short)(r >> 16);
}
__device__ __forceinline__ float bflo(unsigned u) {
  union { unsigned u; float f; } x; x.u = u << 16; return x.f;
}
__device__ __forceinline__ float bfhi(unsigned u) {
  union { unsigned u; float f; } x; x.u = u & 0xffff0000u; return x.f;
}
__device__ __forceinline__ f32x2 up2(unsigned u) {
  f32x2 r; r[0] = bflo(u); r[1] = bfhi(u); return r;
}
__device__ __forceinline__ unsigned pk2(float a, float b) {
  return ((unsigned)(unsigned short)f2bf(b) << 16) | (unsigned)(unsigned short)f2bf(a);
}

// ---------------- fused prep: build_fall + feats gather + weight transposes + smalls ----------------
#define FALL_BLKS 25000
#define FEAT_BLKS 5632
#define PW_BLKS   14336
#define SM_BLKS   10
#define RED_BLKS  384

__global__ __launch_bounds__(256) void mega_prep_kernel(
    short* __restrict__ WqT, short* __restrict__ WkvT, short* __restrict__ WoC,
    short* __restrict__ W1T, short* __restrict__ W1P, short* __restrict__ W2T,
    short* __restrict__ WkQ,
    float* __restrict__ bkv, float* __restrict__ zbias,
    float* __restrict__ qconst, float* __restrict__ b1p, short* __restrict__ f_all,
    short* __restrict__ f_src, short* __restrict__ f_n1,
    const int* __restrict__ src_nodes, const int* __restrict__ n1,
    const float* __restrict__ Wq, const float* __restrict__ Wk, const float* __restrict__ Wv,
    const float* __restrict__ Wo, const float* __restrict__ W1, const float* __restrict__ W2,
    const float* __restrict__ bk, const float* __restrict__ bv, const float* __restrict__ bq,
    const float* __restrict__ bo, const float* __restrict__ b1,
    const float* __restrict__ tb, const float* __restrict__ mem, const float* __restrict__ nf)
{
  int b = blockIdx.x;
  int tid = threadIdx.x;
  if (b < FALL_BLKS) {
    // f_all[node] = bf16(memory + node_features)
    int row = b * 4 + (tid >> 6);
    int c = (tid & 63) * 4;
    f32x4 a = *(const f32x4*)(mem + (size_t)row*256 + c);
    f32x4 d = *(const f32x4*)(nf  + (size_t)row*256 + c);
    short4v o;
#pragma unroll
    for (int e = 0; e < 4; ++e) o[e] = f2bf(a[e] + d[e]);
    *(short4v*)(f_all + (size_t)row*256 + c) = o;
  } else if (b < FALL_BLKS + FEAT_BLKS) {
    // f_src / f_n1 directly from raw tables (same rounding as f_all path)
    int row = (b - FALL_BLKS) * 4 + (tid >> 6);
    int c = (tid & 63) * 4;
    int node; short* dst;
    if (row < BB) { node = src_nodes[row]; dst = f_src + (size_t)row * 256; }
    else { node = n1[row - BB]; dst = f_n1 + (size_t)(row - BB) * 256; }
    f32x4 a = *(const f32x4*)(mem + (size_t)node*256 + c);
    f32x4 d = *(const f32x4*)(nf  + (size_t)node*256 + c);
    short4v o;
#pragma unroll
    for (int e = 0; e < 4; ++e) o[e] = f2bf(a[e] + d[e]);
    *(short4v*)(dst + c) = o;
  } else if (b < FALL_BLKS + FEAT_BLKS + PW_BLKS) {
    const int PER = 512*256 + 1024*768 + 512*512 + 256*768 + 256*256 + 768*512;  // 1835008
    int idx = (b - FALL_BLKS - FEAT_BLKS) * 256 + tid;
    if (idx >= 2 * PER) return;
    int i = idx / PER, r = idx % PER;
    const int S1 = 512*256, S2 = S1 + 1024*768, S3 = S2 + 512*512, S4 = S3 + 256*768,
              S5 = S4 + 256*256;
    if (r < S1) {
      int n = r >> 8, k = r & 255;
      WqT[(size_t)i*S1 + r] = f2bf(Wq[(size_t)i*262144 + (size_t)k*512 + n]);
    } else if (r < S2) {
      int rr = r - S1; int n = rr / 768, k = rr % 768;
      float v = (n < 512) ? Wk[(size_t)i*393216 + (size_t)k*512 + n]
                          : Wv[(size_t)i*393216 + (size_t)k*512 + (n - 512)];
      WkvT[(size_t)i*786432 + rr] = f2bf(v);
    } else if (r < S3) {
      int rr = r - S2;   // straight bf16 copy of Wo (row-major [512][512])
      WoC[(size_t)i*262144 + rr] = f2bf(Wo[(size_t)i*262144 + rr]);
    } else if (r < S4) {
      int rr = r - S3; int n = rr / 768, k = rr % 768;
      short v = f2bf(W1[(size_t)i*196608 + (size_t)k*256 + n]);
      W1T[(size_t)i*196608 + rr] = v;
      if (k >= 512) W1P[(size_t)i*196608 + rr] = v;   // f-part mirrored into folded W1
    } else if (r < S5) {
      int rr = r - S4; int n = rr >> 8, k = rr & 255;
      W2T[(size_t)i*65536 + rr] = f2bf(W2[(size_t)i*65536 + (size_t)k*256 + n]);
    } else {
      // WkQ[i][h][c][d] = Wk[i][c][h*64+d]
      int rr = r - S5; int c = rr >> 9, n = rr & 511, h = n >> 6, d = n & 63;
      WkQ[(size_t)i*393216 + (size_t)h*49152 + (size_t)c*64 + d] =
          f2bf(Wk[(size_t)i*393216 + (size_t)c*512 + n]);
    }
  } else if (b < FALL_BLKS + FEAT_BLKS + PW_BLKS + SM_BLKS) {
    int idx = (b - FALL_BLKS - FEAT_BLKS - PW_BLKS) * 256 + tid;
    if (idx < 2048) {
      int i = idx >> 10, n = idx & 1023;
      bkv[idx] = (n < 512) ? bk[i*512 + n] : bv[i*512 + (n - 512)];
    } else if (idx < 2560) {
      zbias[idx - 2048] = 0.f;
    }
  } else {
    // qconst[o] = bq + sum_t cos(tb[t])*Wq[i][256+t][n] ; b1p[r] = b1 + sum_d bo[d]*W1[i][d][n]
    int w = (b - FALL_BLKS - FEAT_BLKS - PW_BLKS - SM_BLKS) * 4 + (tid >> 6);
    int lane = tid & 63;
    if (w < 1024) {
      int i = w >> 9, n = w & 511;
      float acc = 0.f;
#pragma unroll
      for (int tt = 0; tt < 4; ++tt) {
        int t = lane + tt * 64;
        acc += cosf(tb[t]) * Wq[(size_t)i*262144 + (size_t)(256 + t)*512 + n];
      }
#pragma unroll
      for (int s = 1; s < 64; s <<= 1) acc += __shfl_xor(acc, s);
      if (lane == 0) qconst[w] = acc + bq[i*512 + n];
    } else if (w < 1536) {
      int r = w - 1024;
      int i = r >> 8, n = r & 255;
      float acc = 0.f;
#pragma unroll
      for (int dd = 0; dd < 8; ++dd) {
        int d = lane + dd * 64;
        acc += bo[i*512 + d] * W1[(size_t)i*196608 + (size_t)d*256 + n];
      }
#pragma unroll
      for (int s = 1; s < 64; s <<= 1) acc += __shfl_xor(acc, s);
      if (lane == 0) b1p[r] = acc + b1[i*256 + n];
    }
  }
}

// ---------------- 128x128 GEMM (B switchable at M-row msplitB for fused dual-layer prep) ----------------
template<bool RELU, bool OUTF32>
__global__ __launch_bounds__(256) void gemm128(
    int M, int N, int Kd,
    const short* __restrict__ A1, int lda1, int ksplit,
    const short* __restrict__ A2, int lda2,
    const short* __restrict__ Bt, const short* __restrict__ Bt2, int msplitB,
    const float* __restrict__ bias,
    short* __restrict__ outB, float* __restrict__ outF, int ldo)
{
  __shared__ short As[128][72];
  __shared__ short Bs[128][72];
  const int nbj = N >> 7;
  const int bi = blockIdx.x / nbj;
  const int bj = blockIdx.x % nbj;
  const int tid = threadIdx.x;
  const int lane = tid & 63;
  const int wave = tid >> 6;
  const int wr = (wave >> 1) * 64;
  const int wc = (wave & 1) * 64;

  f32x4 acc[4][4];
  const f32x4 zv = {0.f, 0.f, 0.f, 0.f};
#pragma unroll
  for (int m = 0; m < 4; ++m)
#pragma unroll
    for (int n = 0; n < 4; ++n) acc[m][n] = zv;

  const size_t arow0 = (size_t)bi * 128;
  const short* Bsel = (bi * 128 < msplitB) ? Bt : Bt2;
  const short* Brow = Bsel + (size_t)bj * 128 * (size_t)Kd;

  for (int kt = 0; kt < Kd; kt += 64) {
#pragma unroll
    for (int it = 0; it < 4; ++it) {
      int chunk = tid + it * 256;
      int row = chunk >> 3;
      int c16 = (chunk & 7) * 8;
      int gk = kt + c16;
      const short* srcA;
      if (gk < ksplit) srcA = A1 + (arow0 + row) * (size_t)lda1 + gk;
      else             srcA = A2 + (arow0 + row) * (size_t)lda2 + (gk - ksplit);
      *(short8*)&As[row][c16] = *(const short8*)srcA;
      *(short8*)&Bs[row][c16] = *(const short8*)(Brow + (size_t)row * Kd + kt + c16);
    }
    __syncthreads();
#pragma unroll
    for (int kk = 0; kk < 64; kk += 32) {
      short8 af[4], bfr[4];
#pragma unroll
      for (int m = 0; m < 4; ++m)
        af[m] = *(const short8*)&As[wr + m*16 + (lane & 15)][kk + (lane >> 4) * 8];
#pragma unroll
      for (int n = 0; n < 4; ++n)
        bfr[n] = *(const short8*)&Bs[wc + n*16 + (lane & 15)][kk + (lane >> 4) * 8];
#pragma unroll
      for (int m = 0; m < 4; ++m)
#pragma unroll
        for (int n = 0; n < 4; ++n)
          acc[m][n] = __builtin_amdgcn_mfma_f32_16x16x32_bf16(af[m], bfr[n], acc[m][n], 0, 0, 0);
    }
    __syncthreads();
  }

#pragma unroll
  for (int m = 0; m < 4; ++m) {
#pragma unroll
    for (int r = 0; r < 4; ++r) {
      size_t row = arow0 + wr + m*16 + ((lane >> 4) * 4 + r);
#pragma unroll
      for (int n = 0; n < 4; ++n) {
        int col = bj*128 + wc + n*16 + (lane & 15);
        float v = acc[m][n][r] + bias[col];
        if (RELU) v = v > 0.f ? v : 0.f;
        if (OUTF32) outF[row * (size_t)ldo + col] = v;
        else        outB[row * (size_t)ldo + col] = f2bf(v);
      }
    }
  }
}

// ---------------- qk GEMM: qk[b][h*768+c] = sum_d qh[b][h*64+d] * Wk[c][h*64+d] ----------------
// Epilogue stages the 128x128 bf16 C-tile in LDS, then writes with fully-coalesced 16B
// stores (r12: the old per-element 2B stores put 277 MB through ~32B scattered segments).
__global__ __launch_bounds__(256) void qk_gemm_kernel(
    const short* __restrict__ qh, const short* __restrict__ WkQh,
    short* __restrict__ qk)
{
  __shared__ short As[128][72];
  __shared__ short Bs[128][72];
  __shared__ short Cs[128][132];   // +4 pad: benign banking for both write and read phases
  const int bi = blockIdx.x / 6;
  const int bj = blockIdx.x % 6;
  const int h = blockIdx.y;
  const int tid = threadIdx.x;
  const int lane = tid & 63;
  const int wave = tid >> 6;
  const int wr = (wave >> 1) * 64;
  const int wc = (wave & 1) * 64;

  f32x4 acc[4][4];
  const f32x4 zv = {0.f, 0.f, 0.f, 0.f};
#pragma unroll
  for (int m = 0; m < 4; ++m)
#pragma unroll
    for (int n = 0; n < 4; ++n) acc[m][n] = zv;

#pragma unroll
  for (int it = 0; it < 4; ++it) {
    int chunk = tid + it * 256;
    int row = chunk >> 3;
    int c16 = (chunk & 7) * 8;
    *(short8*)&As[row][c16] = *(const short8*)(qh + (size_t)(bi*128 + row) * 512 + h*64 + c16);
    *(short8*)&Bs[row][c16] = *(const short8*)(WkQh + (size_t)h*49152 + (size_t)(bj*128 + row)*64 + c16);
  }
  __syncthreads();
#pragma unroll
  for (int kk = 0; kk < 64; kk += 32) {
    short8 af[4], bfr[4];
#pragma unroll
    for (int m = 0; m < 4; ++m)
      af[m] = *(const short8*)&As[wr + m*16 + (lane & 15)][kk + (lane >> 4) * 8];
#pragma unroll
    for (int n = 0; n < 4; ++n)
      bfr[n] = *(const short8*)&Bs[wc + n*16 + (lane & 15)][kk + (lane >> 4) * 8];
#pragma unroll
    for (int m = 0; m < 4; ++m)
#pragma unroll
      for (int n = 0; n < 4; ++n)
        acc[m][n] = __builtin_amdgcn_mfma_f32_16x16x32_bf16(af[m], bfr[n], acc[m][n], 0, 0, 0);
  }

  // stage C tile in LDS
#pragma unroll
  for (int m = 0; m < 4; ++m)
#pragma unroll
    for (int r = 0; r < 4; ++r)
#pragma unroll
      for (int n = 0; n < 4; ++n)
        Cs[wr + m*16 + ((lane >> 4) * 4 + r)][wc + n*16 + (lane & 15)] = f2bf(acc[m][n][r]);
  __syncthreads();

  // coalesced 16B stores: thread chunk -> (row, 8-col group)
#pragma unroll
  for (int it = 0; it < 8; ++it) {
    int chunk = tid + it * 256;
    int row = chunk >> 4;
    int c16 = (chunk & 15) * 8;
    size_t grow = (size_t)bi*128 + row;
    *(short8*)(qk + grow * 6144 + (size_t)h * 768 + bj*128 + c16) = *(const short8*)&Cs[row][c16];
  }
}

// ---------------- fused gather + time-enc + scores + softmax + raw-k mixing (v9) ----------------
// v7 structure (best measured: one wave/query, prefetch-all, 2 groups of 4 heads) with the
// score-dot and mixing-accumulate loops on f32x2 pairs (v_pk_fma_f32).
template<int MODE>
__global__ __launch_bounds__(256, 1) void attn_mix9_kernel(
    const short* __restrict__ qk_l, const short* __restrict__ tab,
    const int* __restrict__ nb1, const float* __restrict__ et1, const int* __restrict__ ei1,
    const int* __restrict__ nb2, const float* __restrict__ et2, const int* __restrict__ ei2,
    const float* __restrict__ ts,
    const float* __restrict__ tw, const float* __restrict__ tb,
    const float* __restrict__ ef,
    short* __restrict__ kbar_l, int q0)
{
  int lq = blockIdx.x * 4 + (threadIdx.x >> 6);
  int gq = q0 + lq;
  int lane = threadIdx.x & 63;
  int c4 = lane * 4;

  const int* nbp; const float* etp; const int* eip; float tsq;
  if (MODE == 0) {
    nbp = nb1 + gq*10; etp = et1 + gq*10; eip = ei1 + gq*10; tsq = ts[gq];
  } else {
    if (gq < BB) { nbp = nb1 + gq*10; etp = et1 + gq*10; eip = ei1 + gq*10; tsq = ts[gq]; }
    else {
      int q2 = gq - BB;
      nbp = nb2 + q2*10; etp = et2 + q2*10; eip = ei2 + q2*10; tsq = ts[q2/10];
    }
  }

  // ---- phase 0: indices + edge times (earliest possible issue) ----
  int nb[10]; int ei[10]; float et[10];
#pragma unroll
  for (int j = 0; j < 10; ++j) { nb[j] = nbp[j]; ei[j] = eip[j]; et[j] = etp[j]; }

  f32x4 tw4 = *(const f32x4*)(tw + c4);
  f32x4 tb4 = *(const f32x4*)(tb + c4);

  // ---- phase 1: all 8 heads' qk rows, packed (48 u32, independent of indices) ----
  const short* qkb = qk_l + (size_t)lq * 6144;
  unsigned qp[8][6];
#pragma unroll
  for (int h = 0; h < 8; ++h) {
    const unsigned* p0 = (const unsigned*)(qkb + h*768 + c4);
    const unsigned* p1 = (const unsigned*)(qkb + h*768 + 256 + c4);
    const unsigned* p2 = (const unsigned*)(qkb + h*768 + 512 + c4);
    qp[h][0] = p0[0]; qp[h][1] = p0[1];
    qp[h][2] = p1[0]; qp[h][3] = p1[1];
    qp[h][4] = p2[0]; qp[h][5] = p2[1];
  }

  // ---- phase 2: dependent gathers -> packed k rows kp[j][0:2]=emb, [2:4]=time, [4:6]=edge ----
  unsigned kp[10][6];
  unsigned msk = 0;
#pragma unroll
  for (int j = 0; j < 10; ++j) {
    if (nb[j] == 0) msk |= (1u << j);
    int gi = (MODE == 0) ? (gq*10 + j) : nb[j];
    const unsigned* ep = (const unsigned*)(tab + (size_t)gi*256 + c4);
    kp[j][0] = ep[0];
    kp[j][1] = ep[1];
    float dt = tsq - et[j];
    float t0 = __cosf(dt * tw4[0] + tb4[0]);
    float t1 = __cosf(dt * tw4[1] + tb4[1]);
    float t2 = __cosf(dt * tw4[2] + tb4[2]);
    float t3 = __cosf(dt * tw4[3] + tb4[3]);
    kp[j][2] = pk2(t0, t1);
    kp[j][3] = pk2(t2, t3);
    f32x4 e4 = *(const f32x4*)(ef + (size_t)ei[j]*256 + c4);
    kp[j][4] = pk2(e4[0], e4[1]);
    kp[j][5] = pk2(e4[2], e4[3]);
  }

  short* kbb = kbar_l + (size_t)lq * 6144;
  bool zero = (msk == 0x3ffu);

#pragma unroll
  for (int g = 0; g < 2; ++g) {
    // unpack the 4 heads' qk rows for this group (register-only, f32x2 pairs)
    f32x2 qv2[4][6];
#pragma unroll
    for (int hh = 0; hh < 4; ++hh) {
#pragma unroll
      for (int e = 0; e < 6; ++e) qv2[hh][e] = up2(qp[g*4 + hh][e]);
    }
    // scores: j outer (unpack kp[j] once), 4 heads inner; packed-pair FMA + horizontal add
    float s[4][10];
#pragma unroll
    for (int j = 0; j < 10; ++j) {
      f32x2 kt2[6];
#pragma unroll
      for (int e = 0; e < 6; ++e) kt2[e] = up2(kp[j][e]);
#pragma unroll
      for (int hh = 0; hh < 4; ++hh) {
        f32x2 dp = {0.f, 0.f};
#pragma unroll
        for (int e = 0; e < 6; ++e) dp += qv2[hh][e] * kt2[e];
        float d = dp[0] + dp[1];
        d += __shfl_xor(d, 1);  d += __shfl_xor(d, 2);  d += __shfl_xor(d, 4);
        d += __shfl_xor(d, 8);  d += __shfl_xor(d, 16); d += __shfl_xor(d, 32);
        s[hh][j] = ((msk >> j) & 1u) ? -1e9f : d * 0.125f;
      }
    }
    // softmax per head (p kept unnormalized in s; inv folded at write)
    float inv4[4];
#pragma unroll
    for (int hh = 0; hh < 4; ++hh) {
      float mx = s[hh][0];
#pragma unroll
      for (int j = 1; j < 10; ++j) mx = fmaxf(mx, s[hh][j]);
      float sum = 0.f;
#pragma unroll
      for (int j = 0; j < 10; ++j) { s[hh][j] = __expf(s[hh][j] - mx); sum += s[hh][j]; }
      inv4[hh] = 1.f / sum;
    }
    // mixing: j outer (unpack kp[j] once), accumulate 4 heads with packed-pair FMA
    f32x2 ac2[4][6];
#pragma unroll
    for (int hh = 0; hh < 4; ++hh)
#pragma unroll
      for (int e = 0; e < 6; ++e) ac2[hh][e] = (f32x2){0.f, 0.f};
#pragma unroll
    for (int j = 0; j < 10; ++j) {
      f32x2 kt2[6];
#pragma unroll
      for (int e = 0; e < 6; ++e) kt2[e] = up2(kp[j][e]);
#pragma unroll
      for (int hh = 0; hh < 4; ++hh) {
        f32x2 pj2 = {s[hh][j], s[hh][j]};
#pragma unroll
        for (int e = 0; e < 6; ++e) ac2[hh][e] += pj2 * kt2[e];
      }
    }
#pragma unroll
    for (int hh = 0; hh < 4; ++hh) {
      float inv = inv4[hh];
      short4v o0, o1, o2;
#pragma unroll
      for (int e = 0; e < 2; ++e) {
        o0[2*e]   = zero ? (short)0 : f2bf(ac2[hh][e][0] * inv);
        o0[2*e+1] = zero ? (short)0 : f2bf(ac2[hh][e][1] * inv);
        o1[2*e]   = zero ? (short)0 : f2bf(ac2[hh][2+e][0] * inv);
        o1[2*e+1] = zero ? (short)0 : f2bf(ac2[hh][2+e][1] * inv);
        o2[2*e]   = zero ? (short)0 : f2bf(ac2[hh][4+e][0] * inv);
        o2[2*e+1] = zero ? (short)0 : f2bf(ac2[hh][4+e][1] * inv);
      }
      short* kb = kbb + (g*4 + hh)*768;
      *(short4v*)(kb + c4)       = o0;
      *(short4v*)(kb + 256 + c4) = o1;
      *(short4v*)(kb + 512 + c4) = o2;
    }
  }
}

// ---------------- per-head o-projection: out[b][h*64+n] = kbar[b][h]·Wv_h + bv_h ----------------
__global__ __launch_bounds__(256) void gemm_n64_kernel(
    int M, int Kd,
    const short* __restrict__ A, int lda,
    const short* __restrict__ Bt,
    const float* __restrict__ bias,
    short* __restrict__ out, int ldo)
{
  __shared__ short As[128][72];
  __shared__ short Bs[64][72];
  const int bi = blockIdx.x;
  const int h = blockIdx.y;
  const int tid = threadIdx.x;
  const int lane = tid & 63;
  const int wave = tid >> 6;

  const short* Ah = A + (size_t)h * 768;
  const short* Bh = Bt + (size_t)h * 64 * (size_t)Kd;
  const float* biash = bias + h * 64;
  short* outh = out + h * 64;

  f32x4 acc[2][4];
  const f32x4 zv = {0.f, 0.f, 0.f, 0.f};
#pragma unroll
  for (int m = 0; m < 2; ++m)
#pragma unroll
    for (int n = 0; n < 4; ++n) acc[m][n] = zv;

  const size_t arow0 = (size_t)bi * 128;
  for (int kt = 0; kt < Kd; kt += 64) {
#pragma unroll
    for (int it = 0; it < 4; ++it) {
      int chunk = tid + it * 256;
      int row = chunk >> 3;
      int c16 = (chunk & 7) * 8;
      *(short8*)&As[row][c16] = *(const short8*)(Ah + (arow0 + row) * (size_t)lda + kt + c16);
    }
#pragma unroll
    for (int it = 0; it < 2; ++it) {
      int chunk = tid + it * 256;
      int row = chunk >> 3;
      int c16 = (chunk & 7) * 8;
      *(short8*)&Bs[row][c16] = *(const short8*)(Bh + (size_t)row * Kd + kt + c16);
    }
    __syncthreads();
#pragma unroll
    for (int kk = 0; kk < 64; kk += 32) {
      short8 af[2], bfr[4];
#pragma unroll
      for (int m = 0; m < 2; ++m)
        af[m] = *(const short8*)&As[wave*32 + m*16 + (lane & 15)][kk + (lane >> 4) * 8];
#pragma unroll
      for (int n = 0; n < 4; ++n)
        bfr[n] = *(const short8*)&Bs[n*16 + (lane & 15)][kk + (lane >> 4) * 8];
#pragma unroll
      for (int m = 0; m < 2; ++m)
#pragma unroll
        for (int n = 0; n < 4; ++n)
          acc[m][n] = __builtin_amdgcn_mfma_f32_16x16x32_bf16(af[m], bfr[n], acc[m][n], 0, 0, 0);
    }
    __syncthreads();
  }

#pragma unroll
  for (int m = 0; m < 2; ++m) {
#pragma unroll
    for (int r = 0; r < 4; ++r) {
      size_t row = arow0 + wave*32 + m*16 + ((lane >> 4) * 4 + r);
#pragma unroll
      for (int n = 0; n < 4; ++n) {
        int col = n*16 + (lane & 15);
        outh[row * (size_t)ldo + col] = f2bf(acc[m][n][r] + biash[col]);
      }
    }
  }
}

// ---------------- fused MergeLayer: out = relu(A@W1P+b1p) @ W2T + b2 ----------------
template<bool OUTF32>
__global__ __launch_bounds__(256) void w12_kernel(
    const short* __restrict__ A1,      // obuf rows [*][512]
    const short* __restrict__ A2,      // feat rows [*][256] (K 512..767)
    const short* __restrict__ B1,      // W1P [256][768]
    const float* __restrict__ bias1,   // b1p [256]
    const short* __restrict__ B2,      // W2T [256][256]
    const float* __restrict__ bias2,   // b2  [256]
    short* __restrict__ outB, float* __restrict__ outF)
{
  __shared__ short As[128][72];
  __shared__ short Bs[256][72];
  __shared__ short C1[128][280];
  const int tid = threadIdx.x;
  const int lane = tid & 63;
  const int wave = tid >> 6;
  const int wr = (wave >> 1) * 64;
  const int wc = (wave & 1) * 128;
  const size_t arow0 = (size_t)blockIdx.x * 128;

  f32x4 acc[4][8];
  const f32x4 zv = {0.f, 0.f, 0.f, 0.f};
#pragma unroll
  for (int m = 0; m < 4; ++m)
#pragma unroll
    for (int n = 0; n < 8; ++n) acc[m][n] = zv;

  // ---- phase 1: C1 = relu(A @ W1P + b1p), K=768, N=256 ----
  for (int kt = 0; kt < 768; kt += 64) {
#pragma unroll
    for (int it = 0; it < 4; ++it) {
      int chunk = tid + it * 256;
      int row = chunk >> 3;
      int c16 = (chunk & 7) * 8;
      int gk = kt + c16;
      const short* srcA;
      if (gk < 512) srcA = A1 + (arow0 + row) * 512 + gk;
      else          srcA = A2 + (arow0 + row) * 256 + (gk - 512);
      *(short8*)&As[row][c16] = *(const short8*)srcA;
    }
#pragma unroll
    for (int it = 0; it < 8; ++it) {
      int chunk = tid + it * 256;
      int row = chunk >> 3;
      int c16 = (chunk & 7) * 8;
      *(short8*)&Bs[row][c16] = *(const short8*)(B1 + (size_t)row * 768 + kt + c16);
    }
    __syncthreads();
#pragma unroll
    for (int kk = 0; kk < 64; kk += 32) {
      short8 af[4], bfr[8];
#pragma unroll
      for (int m = 0; m < 4; ++m)
        af[m] = *(const short8*)&As[wr + m*16 + (lane & 15)][kk + (lane >> 4) * 8];
#pragma unroll
      for (int n = 0; n < 8; ++n)
        bfr[n] = *(const short8*)&Bs[wc + n*16 + (lane & 15)][kk + (lane >> 4) * 8];
#pragma unroll
      for (int m = 0; m < 4; ++m)
#pragma unroll
        for (int n = 0; n < 8; ++n)
          acc[m][n] = __builtin_amdgcn_mfma_f32_16x16x32_bf16(af[m], bfr[n], acc[m][n], 0, 0, 0);
    }
    __syncthreads();
  }
#pragma unroll
  for (int m = 0; m < 4; ++m) {
#pragma unroll
    for (int r = 0; r < 4; ++r) {
      int row = wr + m*16 + ((lane >> 4) * 4 + r);
#pragma unroll
      for (int n = 0; n < 8; ++n) {
        int col = wc + n*16 + (lane & 15);
        float v = acc[m][n][r] + bias1[col];
        C1[row][col] = f2bf(v > 0.f ? v : 0.f);
        acc[m][n][r] = 0.f;
      }
    }
  }
  __syncthreads();

  // ---- phase 2: out = C1 @ W2T + b2, K=256, N=256 ----
  for (int kt = 0; kt < 256; kt += 64) {
#pragma unroll
    for (int it = 0; it < 8; ++it) {
      int chunk = tid + it * 256;
      int row = chunk >> 3;
      int c16 = (chunk & 7) * 8;
      *(short8*)&Bs[row][c16] = *(const short8*)(B2 + (size_t)row * 256 + kt + c16);
    }
    __syncthreads();
#pragma unroll
    for (int kk = 0; kk < 64; kk += 32) {
      short8 af[4], bfr[8];
#pragma unroll
      for (int m = 0; m < 4; ++m)
        af[m] = *(const short8*)&C1[wr + m*16 + (lane & 15)][kt + kk + (lane >> 4) * 8];
#pragma unroll
      for (int n = 0; n < 8; ++n)
        bfr[n] = *(const short8*)&Bs[wc + n*16 + (lane & 15)][kk + (lane >> 4) * 8];
#pragma unroll
      for (int m = 0; m < 4; ++m)
#pragma unroll
        for (int n = 0; n < 8; ++n)
          acc[m][n] = __builtin_amdgcn_mfma_f32_16x16x32_bf16(af[m], bfr[n], acc[m][n], 0, 0, 0);
    }
    __syncthreads();
  }
#pragma unroll
  for (int m = 0; m < 4; ++m) {
#pragma unroll
    for (int r = 0; r < 4; ++r) {
      size_t row = arow0 + wr + m*16 + ((lane >> 4) * 4 + r);
#pragma unroll
      for (int n = 0; n < 8; ++n) {
        int col = wc + n*16 + (lane & 15);
        float v = acc[m][n][r] + bias2[col];
        if (OUTF32) outF[row * 256 + col] = v;
        else        outB[row * 256 + col] = f2bf(v);
      }
    }
  }
}

// =======================================================================
extern "C" void kernel_launch(void* const* d_in, const int* in_sizes, int n_in,
                              void* d_out, int out_size, void* d_ws, size_t ws_size,
                              hipStream_t stream)
{
  const float* memory   = (const float*)d_in[0];
  const float* node_f   = (const float*)d_in[1];
  const float* edge_f   = (const float*)d_in[2];
  const float* time_w   = (const float*)d_in[3];
  const float* time_b   = (const float*)d_in[4];
  const float* Wq = (const float*)d_in[5];
  const float* bq = (const float*)d_in[6];
  const float* Wk = (const float*)d_in[7];
  const float* bk = (const float*)d_in[8];
  const float* Wv = (const float*)d_in[9];
  const float* bv = (const float*)d_in[10];
  const float* Wo = (const float*)d_in[11];
  const float* bo = (const float*)d_in[12];
  const float* W1 = (const float*)d_in[13];
  const float* b1 = (const float*)d_in[14];
  const float* W2 = (const float*)d_in[15];
  const float* b2 = (const float*)d_in[16];
  const float* timestamps = (const float*)d_in[17];
  const float* et1 = (const float*)d_in[18];
  const float* et2 = (const float*)d_in[19];
  const int* src_nodes  = (const int*)d_in[20];
  const int* neighbors1 = (const int*)d_in[21];
  const int* edge_idx1  = (const int*)d_in[22];
  const int* neighbors2 = (const int*)d_in[23];
  const int* edge_idx2  = (const int*)d_in[24];
  float* out = (float*)d_out;

  char* wsp = (char*)d_ws;
  size_t off = 0;
  auto alloc = [&](size_t bytes) -> void* {
    void* p = wsp + off;
    off += (bytes + 255) & ~(size_t)255;
    return p;
  };
  short* WqT  = (short*)alloc((size_t)2*512*256*2);
  short* WkvT = (short*)alloc((size_t)2*1024*768*2);
  short* WoC  = (short*)alloc((size_t)2*512*512*2);
  short* W1T  = (short*)alloc((size_t)2*256*768*2);
  short* W1P  = (short*)alloc((size_t)2*256*768*2);
  short* W2T  = (short*)alloc((size_t)2*256*256*2);
  short* WkQ  = (short*)alloc((size_t)2*768*512*2);
  float* qconst = (float*)alloc(2*512*4);
  float* bkv    = (float*)alloc(2*1024*4);
  float* b1p    = (float*)alloc(2*256*4);
  float* zbias  = (float*)alloc(512*4);
  short* f_all  = (short*)alloc((size_t)NNODES*256*2);
  short* f_src  = (short*)alloc((size_t)BB*256*2);    // f_src‖f_n1 contiguous
  short* f_n1   = (short*)alloc((size_t)N1R*256*2);
  short* src_l1 = (short*)alloc((size_t)BB*256*2);    // src_l1‖n1_l1 contiguous
  short* n1_l1  = (short*)alloc((size_t)N1R*256*2);
  short* qh     = (short*)alloc((size_t)Q2T*512*2);
  short* obuf   = (short*)alloc((size_t)Q2T*512*2);
  size_t fixed = off;

  // attention intermediates: UNCHUNKED (r8 measured chunking at CB=5632 costs +76 us).
  int CB = 2048;
  {
    const int cands[5] = {22528, 11264, 5632, 2816, 2048};
    for (int c = 0; c < 5; ++c) {
      size_t need = fixed
        + (((size_t)cands[c]*6144*2 + 255) & ~(size_t)255)
        + (((size_t)cands[c]*6144*2 + 255) & ~(size_t)255);
      if (need <= ws_size) { CB = cands[c]; break; }
    }
  }
  short* qkbuf = (short*)alloc((size_t)CB*6144*2);
  short* kbar  = (short*)alloc((size_t)CB*6144*2);

  const int BIG = 1 << 30;
  // ---- fused prep (1 dispatch) ----
  mega_prep_kernel<<<dim3(FALL_BLKS + FEAT_BLKS + PW_BLKS + SM_BLKS + RED_BLKS), dim3(256), 0, stream>>>(
      WqT, WkvT, WoC, W1T, W1P, W2T, WkQ, bkv, zbias, qconst, b1p, f_all,
      f_src, f_n1, src_nodes, neighbors1,
      Wq, Wk, Wv, Wo, W1, W2, bk, bv, bq, bo, b1, time_b, memory, node_f);
  // ---- W1P[:,0:512] for BOTH layers in one dispatch (M=512 spans i; B switches at row 256) ----
  gemm128<false,false><<<dim3(16), dim3(256), 0, stream>>>(
      512, 512, 512, W1T, 768, 512, W1T, 768, WoC, WoC + 262144, 256, zbias, W1P, nullptr, 768);

  // ---- merged calls 1+2 (layer-0 attention over 22528 queries) ----
  gemm128<false,false><<<dim3((Q2T/128)*4), dim3(256), 0, stream>>>(
      Q2T, 512, 256, f_src, 256, 256, f_src, 256, WqT, WqT, BIG, qconst, qh, nullptr, 512);
  for (int b0 = 0; b0 < Q2T; b0 += CB) {
    qk_gemm_kernel<<<dim3((CB/128)*6, 8), dim3(256), 0, stream>>>(
        qh + (size_t)b0*512, WkQ, qkbuf);
    attn_mix9_kernel<1><<<dim3(CB/4), dim3(256), 0, stream>>>(
        qkbuf, f_all, neighbors1, et1, edge_idx1, neighbors2, et2, edge_idx2,
        timestamps, time_w, time_b, edge_f, kbar, b0);
    gemm_n64_kernel<<<dim3(CB/128, 8), dim3(256), 0, stream>>>(
        CB, 768, kbar, 6144, WkvT + 512*768, bkv + 512, obuf + (size_t)b0*512, 512);
  }
  w12_kernel<false><<<dim3(Q2T/128), dim3(256), 0, stream>>>(
      obuf, f_src, W1P, b1p, W2T, b2, src_l1, nullptr);

  // ---- call 3: out = attn(1, src_l1, n1_l1, dt1, ef1, m1) ----
  gemm128<false,false><<<dim3((BB/128)*4), dim3(256), 0, stream>>>(
      BB, 512, 256, src_l1, 256, 256, src_l1, 256, WqT + 512*256, WqT + 512*256, BIG,
      qconst + 512, qh, nullptr, 512);
  qk_gemm_kernel<<<dim3((BB/128)*6, 8), dim3(256), 0, stream>>>(qh, WkQ + 393216, qkbuf);
  attn_mix9_kernel<0><<<dim3(BB/4), dim3(256), 0, stream>>>(
      qkbuf, n1_l1, neighbors1, et1, edge_idx1, neighbors1, et1, edge_idx1,
      timestamps, time_w, time_b, edge_f, kbar, 0);
  gemm_n64_kernel<<<dim3(BB/128, 8), dim3(256), 0, stream>>>(
      BB, 768, kbar, 6144, WkvT + 786432 + 512*768, bkv + 1024 + 512, obuf, 512);
  w12_kernel<true><<<dim3(BB/128), dim3(256), 0, stream>>>(
      obuf, src_l1, W1P + 196608, b1p + 256, W2T + 65536, b2 + 256, nullptr, out);
}

// Round 13
// 674.306 us; speedup vs baseline: 1.0131x; 1.0131x over previous
//
#include <hip/hip_runtime.h>
#include <hip/hip_bf16.h>
#include <math.h>

#define BB 2048
#define KK 10
#define N1R 20480
#define Q2T 22528          // BB + N1R merged query rows
#define NNODES 100000

typedef short short4v __attribute__((ext_vector_type(4)));
typedef short short8 __attribute__((ext_vector_type(8)));
typedef float f32x4 __attribute__((ext_vector_type(4)));
typedef float f32x2 __attribute__((ext_vector_type(2)));

__device__ __forceinline__ float bf2f(short s) {
  union { unsigned u; float f; } x;
  x.u = ((unsigned)(unsigned short)s) << 16;
  return x.f;
}
__device__ __forceinline__ short f2bf(float f) {
  union { float f; unsigned u; } x;
  x.f = f;
  unsigned r = x.u + 0x7fffu + ((x.u >> 16) & 1u);
  return (short)(r >> 16);
}
__device__ __forceinline__ float bflo(unsigned u) {
  union { unsigned u; float f; } x; x.u = u << 16; return x.f;
}
__device__ __forceinline__ float bfhi(unsigned u) {
  union { unsigned u; float f; } x; x.u = u & 0xffff0000u; return x.f;
}
__device__ __forceinline__ f32x2 up2(unsigned u) {
  f32x2 r; r[0] = bflo(u); r[1] = bfhi(u); return r;
}
__device__ __forceinline__ unsigned pk2(float a, float b) {
  return ((unsigned)(unsigned short)f2bf(b) << 16) | (unsigned)(unsigned short)f2bf(a);
}

// ---------------- fused prep: build_fall + feats gather + weight transposes + smalls ----------------
#define FALL_BLKS 25000
#define FEAT_BLKS 5632
#define PW_BLKS   14336
#define SM_BLKS   10
#define RED_BLKS  384

__global__ __launch_bounds__(256) void mega_prep_kernel(
    short* __restrict__ WqT, short* __restrict__ WkvT, short* __restrict__ WoC,
    short* __restrict__ W1T, short* __restrict__ W1P, short* __restrict__ W2T,
    short* __restrict__ WkQ,
    float* __restrict__ bkv, float* __restrict__ zbias,
    float* __restrict__ qconst, float* __restrict__ b1p, short* __restrict__ f_all,
    short* __restrict__ f_src, short* __restrict__ f_n1,
    const int* __restrict__ src_nodes, const int* __restrict__ n1,
    const float* __restrict__ Wq, const float* __restrict__ Wk, const float* __restrict__ Wv,
    const float* __restrict__ Wo, const float* __restrict__ W1, const float* __restrict__ W2,
    const float* __restrict__ bk, const float* __restrict__ bv, const float* __restrict__ bq,
    const float* __restrict__ bo, const float* __restrict__ b1,
    const float* __restrict__ tb, const float* __restrict__ mem, const float* __restrict__ nf)
{
  int b = blockIdx.x;
  int tid = threadIdx.x;
  if (b < FALL_BLKS) {
    // f_all[node] = bf16(memory + node_features)
    int row = b * 4 + (tid >> 6);
    int c = (tid & 63) * 4;
    f32x4 a = *(const f32x4*)(mem + (size_t)row*256 + c);
    f32x4 d = *(const f32x4*)(nf  + (size_t)row*256 + c);
    short4v o;
#pragma unroll
    for (int e = 0; e < 4; ++e) o[e] = f2bf(a[e] + d[e]);
    *(short4v*)(f_all + (size_t)row*256 + c) = o;
  } else if (b < FALL_BLKS + FEAT_BLKS) {
    // f_src / f_n1 directly from raw tables (same rounding as f_all path)
    int row = (b - FALL_BLKS) * 4 + (tid >> 6);
    int c = (tid & 63) * 4;
    int node; short* dst;
    if (row < BB) { node = src_nodes[row]; dst = f_src + (size_t)row * 256; }
    else { node = n1[row - BB]; dst = f_n1 + (size_t)(row - BB) * 256; }
    f32x4 a = *(const f32x4*)(mem + (size_t)node*256 + c);
    f32x4 d = *(const f32x4*)(nf  + (size_t)node*256 + c);
    short4v o;
#pragma unroll
    for (int e = 0; e < 4; ++e) o[e] = f2bf(a[e] + d[e]);
    *(short4v*)(dst + c) = o;
  } else if (b < FALL_BLKS + FEAT_BLKS + PW_BLKS) {
    const int PER = 512*256 + 1024*768 + 512*512 + 256*768 + 256*256 + 768*512;  // 1835008
    int idx = (b - FALL_BLKS - FEAT_BLKS) * 256 + tid;
    if (idx >= 2 * PER) return;
    int i = idx / PER, r = idx % PER;
    const int S1 = 512*256, S2 = S1 + 1024*768, S3 = S2 + 512*512, S4 = S3 + 256*768,
              S5 = S4 + 256*256;
    if (r < S1) {
      int n = r >> 8, k = r & 255;
      WqT[(size_t)i*S1 + r] = f2bf(Wq[(size_t)i*262144 + (size_t)k*512 + n]);
    } else if (r < S2) {
      int rr = r - S1; int n = rr / 768, k = rr % 768;
      float v = (n < 512) ? Wk[(size_t)i*393216 + (size_t)k*512 + n]
                          : Wv[(size_t)i*393216 + (size_t)k*512 + (n - 512)];
      WkvT[(size_t)i*786432 + rr] = f2bf(v);
    } else if (r < S3) {
      int rr = r - S2;   // straight bf16 copy of Wo (row-major [512][512])
      WoC[(size_t)i*262144 + rr] = f2bf(Wo[(size_t)i*262144 + rr]);
    } else if (r < S4) {
      int rr = r - S3; int n = rr / 768, k = rr % 768;
      short v = f2bf(W1[(size_t)i*196608 + (size_t)k*256 + n]);
      W1T[(size_t)i*196608 + rr] = v;
      if (k >= 512) W1P[(size_t)i*196608 + rr] = v;   // f-part mirrored into folded W1
    } else if (r < S5) {
      int rr = r - S4; int n = rr >> 8, k = rr & 255;
      W2T[(size_t)i*65536 + rr] = f2bf(W2[(size_t)i*65536 + (size_t)k*256 + n]);
    } else {
      // WkQ[i][h][c][d] = Wk[i][c][h*64+d]
      int rr = r - S5; int c = rr >> 9, n = rr & 511, h = n >> 6, d = n & 63;
      WkQ[(size_t)i*393216 + (size_t)h*49152 + (size_t)c*64 + d] =
          f2bf(Wk[(size_t)i*393216 + (size_t)c*512 + n]);
    }
  } else if (b < FALL_BLKS + FEAT_BLKS + PW_BLKS + SM_BLKS) {
    int idx = (b - FALL_BLKS - FEAT_BLKS - PW_BLKS) * 256 + tid;
    if (idx < 2048) {
      int i = idx >> 10, n = idx & 1023;
      bkv[idx] = (n < 512) ? bk[i*512 + n] : bv[i*512 + (n - 512)];
    } else if (idx < 2560) {
      zbias[idx - 2048] = 0.f;
    }
  } else {
    // qconst[o] = bq + sum_t cos(tb[t])*Wq[i][256+t][n] ; b1p[r] = b1 + sum_d bo[d]*W1[i][d][n]
    int w = (b - FALL_BLKS - FEAT_BLKS - PW_BLKS - SM_BLKS) * 4 + (tid >> 6);
    int lane = tid & 63;
    if (w < 1024) {
      int i = w >> 9, n = w & 511;
      float acc = 0.f;
#pragma unroll
      for (int tt = 0; tt < 4; ++tt) {
        int t = lane + tt * 64;
        acc += cosf(tb[t]) * Wq[(size_t)i*262144 + (size_t)(256 + t)*512 + n];
      }
#pragma unroll
      for (int s = 1; s < 64; s <<= 1) acc += __shfl_xor(acc, s);
      if (lane == 0) qconst[w] = acc + bq[i*512 + n];
    } else if (w < 1536) {
      int r = w - 1024;
      int i = r >> 8, n = r & 255;
      float acc = 0.f;
#pragma unroll
      for (int dd = 0; dd < 8; ++dd) {
        int d = lane + dd * 64;
        acc += bo[i*512 + d] * W1[(size_t)i*196608 + (size_t)d*256 + n];
      }
#pragma unroll
      for (int s = 1; s < 64; s <<= 1) acc += __shfl_xor(acc, s);
      if (lane == 0) b1p[r] = acc + b1[i*256 + n];
    }
  }
}

// ---------------- 128x128 GEMM (B switchable at M-row msplitB for fused dual-layer prep) ----------------
template<bool RELU, bool OUTF32>
__global__ __launch_bounds__(256) void gemm128(
    int M, int N, int Kd,
    const short* __restrict__ A1, int lda1, int ksplit,
    const short* __restrict__ A2, int lda2,
    const short* __restrict__ Bt, const short* __restrict__ Bt2, int msplitB,
    const float* __restrict__ bias,
    short* __restrict__ outB, float* __restrict__ outF, int ldo)
{
  __shared__ short As[128][72];
  __shared__ short Bs[128][72];
  const int nbj = N >> 7;
  const int bi = blockIdx.x / nbj;
  const int bj = blockIdx.x % nbj;
  const int tid = threadIdx.x;
  const int lane = tid & 63;
  const int wave = tid >> 6;
  const int wr = (wave >> 1) * 64;
  const int wc = (wave & 1) * 64;

  f32x4 acc[4][4];
  const f32x4 zv = {0.f, 0.f, 0.f, 0.f};
#pragma unroll
  for (int m = 0; m < 4; ++m)
#pragma unroll
    for (int n = 0; n < 4; ++n) acc[m][n] = zv;

  const size_t arow0 = (size_t)bi * 128;
  const short* Bsel = (bi * 128 < msplitB) ? Bt : Bt2;
  const short* Brow = Bsel + (size_t)bj * 128 * (size_t)Kd;

  for (int kt = 0; kt < Kd; kt += 64) {
#pragma unroll
    for (int it = 0; it < 4; ++it) {
      int chunk = tid + it * 256;
      int row = chunk >> 3;
      int c16 = (chunk & 7) * 8;
      int gk = kt + c16;
      const short* srcA;
      if (gk < ksplit) srcA = A1 + (arow0 + row) * (size_t)lda1 + gk;
      else             srcA = A2 + (arow0 + row) * (size_t)lda2 + (gk - ksplit);
      *(short8*)&As[row][c16] = *(const short8*)srcA;
      *(short8*)&Bs[row][c16] = *(const short8*)(Brow + (size_t)row * Kd + kt + c16);
    }
    __syncthreads();
#pragma unroll
    for (int kk = 0; kk < 64; kk += 32) {
      short8 af[4], bfr[4];
#pragma unroll
      for (int m = 0; m < 4; ++m)
        af[m] = *(const short8*)&As[wr + m*16 + (lane & 15)][kk + (lane >> 4) * 8];
#pragma unroll
      for (int n = 0; n < 4; ++n)
        bfr[n] = *(const short8*)&Bs[wc + n*16 + (lane & 15)][kk + (lane >> 4) * 8];
#pragma unroll
      for (int m = 0; m < 4; ++m)
#pragma unroll
        for (int n = 0; n < 4; ++n)
          acc[m][n] = __builtin_amdgcn_mfma_f32_16x16x32_bf16(af[m], bfr[n], acc[m][n], 0, 0, 0);
    }
    __syncthreads();
  }

#pragma unroll
  for (int m = 0; m < 4; ++m) {
#pragma unroll
    for (int r = 0; r < 4; ++r) {
      size_t row = arow0 + wr + m*16 + ((lane >> 4) * 4 + r);
#pragma unroll
      for (int n = 0; n < 4; ++n) {
        int col = bj*128 + wc + n*16 + (lane & 15);
        float v = acc[m][n][r] + bias[col];
        if (RELU) v = v > 0.f ? v : 0.f;
        if (OUTF32) outF[row * (size_t)ldo + col] = v;
        else        outB[row * (size_t)ldo + col] = f2bf(v);
      }
    }
  }
}

// ---------------- qk GEMM: qk[b][h*768+c] = sum_d qh[b][h*64+d] * Wk[c][h*64+d] ----------------
// LDS-staged epilogue with coalesced 16B stores (r12; perf-neutral but keeps stores clean).
__global__ __launch_bounds__(256) void qk_gemm_kernel(
    const short* __restrict__ qh, const short* __restrict__ WkQh,
    short* __restrict__ qk)
{
  __shared__ short As[128][72];
  __shared__ short Bs[128][72];
  __shared__ short Cs[128][132];
  const int bi = blockIdx.x / 6;
  const int bj = blockIdx.x % 6;
  const int h = blockIdx.y;
  const int tid = threadIdx.x;
  const int lane = tid & 63;
  const int wave = tid >> 6;
  const int wr = (wave >> 1) * 64;
  const int wc = (wave & 1) * 64;

  f32x4 acc[4][4];
  const f32x4 zv = {0.f, 0.f, 0.f, 0.f};
#pragma unroll
  for (int m = 0; m < 4; ++m)
#pragma unroll
    for (int n = 0; n < 4; ++n) acc[m][n] = zv;

#pragma unroll
  for (int it = 0; it < 4; ++it) {
    int chunk = tid + it * 256;
    int row = chunk >> 3;
    int c16 = (chunk & 7) * 8;
    *(short8*)&As[row][c16] = *(const short8*)(qh + (size_t)(bi*128 + row) * 512 + h*64 + c16);
    *(short8*)&Bs[row][c16] = *(const short8*)(WkQh + (size_t)h*49152 + (size_t)(bj*128 + row)*64 + c16);
  }
  __syncthreads();
#pragma unroll
  for (int kk = 0; kk < 64; kk += 32) {
    short8 af[4], bfr[4];
#pragma unroll
    for (int m = 0; m < 4; ++m)
      af[m] = *(const short8*)&As[wr + m*16 + (lane & 15)][kk + (lane >> 4) * 8];
#pragma unroll
    for (int n = 0; n < 4; ++n)
      bfr[n] = *(const short8*)&Bs[wc + n*16 + (lane & 15)][kk + (lane >> 4) * 8];
#pragma unroll
    for (int m = 0; m < 4; ++m)
#pragma unroll
      for (int n = 0; n < 4; ++n)
        acc[m][n] = __builtin_amdgcn_mfma_f32_16x16x32_bf16(af[m], bfr[n], acc[m][n], 0, 0, 0);
  }

  // stage C tile in LDS
#pragma unroll
  for (int m = 0; m < 4; ++m)
#pragma unroll
    for (int r = 0; r < 4; ++r)
#pragma unroll
      for (int n = 0; n < 4; ++n)
        Cs[wr + m*16 + ((lane >> 4) * 4 + r)][wc + n*16 + (lane & 15)] = f2bf(acc[m][n][r]);
  __syncthreads();

  // coalesced 16B stores: thread chunk -> (row, 8-col group)
#pragma unroll
  for (int it = 0; it < 8; ++it) {
    int chunk = tid + it * 256;
    int row = chunk >> 4;
    int c16 = (chunk & 15) * 8;
    size_t grow = (size_t)bi*128 + row;
    *(short8*)(qk + grow * 6144 + (size_t)h * 768 + bj*128 + c16) = *(const short8*)&Cs[row][c16];
  }
}

// ---------------- fused gather + time-enc + scores + softmax + raw-k mixing (v10) ----------------
// v9 (r11) + s_setprio(1) around the per-group compute phases (T5): mix waves are
// barrier-free and independently phased, so compute-phase waves can be preferred over
// gather-issuing waves on the SIMD scheduler (catalog m191: +4-7% on independent-wave attn;
// null only on lockstep GEMMs). Zero arithmetic change.
template<int MODE>
__global__ __launch_bounds__(256, 1) void attn_mix10_kernel(
    const short* __restrict__ qk_l, const short* __restrict__ tab,
    const int* __restrict__ nb1, const float* __restrict__ et1, const int* __restrict__ ei1,
    const int* __restrict__ nb2, const float* __restrict__ et2, const int* __restrict__ ei2,
    const float* __restrict__ ts,
    const float* __restrict__ tw, const float* __restrict__ tb,
    const float* __restrict__ ef,
    short* __restrict__ kbar_l, int q0)
{
  int lq = blockIdx.x * 4 + (threadIdx.x >> 6);
  int gq = q0 + lq;
  int lane = threadIdx.x & 63;
  int c4 = lane * 4;

  const int* nbp; const float* etp; const int* eip; float tsq;
  if (MODE == 0) {
    nbp = nb1 + gq*10; etp = et1 + gq*10; eip = ei1 + gq*10; tsq = ts[gq];
  } else {
    if (gq < BB) { nbp = nb1 + gq*10; etp = et1 + gq*10; eip = ei1 + gq*10; tsq = ts[gq]; }
    else {
      int q2 = gq - BB;
      nbp = nb2 + q2*10; etp = et2 + q2*10; eip = ei2 + q2*10; tsq = ts[q2/10];
    }
  }

  // ---- phase 0: indices + edge times (earliest possible issue) ----
  int nb[10]; int ei[10]; float et[10];
#pragma unroll
  for (int j = 0; j < 10; ++j) { nb[j] = nbp[j]; ei[j] = eip[j]; et[j] = etp[j]; }

  f32x4 tw4 = *(const f32x4*)(tw + c4);
  f32x4 tb4 = *(const f32x4*)(tb + c4);

  // ---- phase 1: all 8 heads' qk rows, packed (48 u32, independent of indices) ----
  const short* qkb = qk_l + (size_t)lq * 6144;
  unsigned qp[8][6];
#pragma unroll
  for (int h = 0; h < 8; ++h) {
    const unsigned* p0 = (const unsigned*)(qkb + h*768 + c4);
    const unsigned* p1 = (const unsigned*)(qkb + h*768 + 256 + c4);
    const unsigned* p2 = (const unsigned*)(qkb + h*768 + 512 + c4);
    qp[h][0] = p0[0]; qp[h][1] = p0[1];
    qp[h][2] = p1[0]; qp[h][3] = p1[1];
    qp[h][4] = p2[0]; qp[h][5] = p2[1];
  }

  // ---- phase 2: dependent gathers -> packed k rows kp[j][0:2]=emb, [2:4]=time, [4:6]=edge ----
  unsigned kp[10][6];
  unsigned msk = 0;
#pragma unroll
  for (int j = 0; j < 10; ++j) {
    if (nb[j] == 0) msk |= (1u << j);
    int gi = (MODE == 0) ? (gq*10 + j) : nb[j];
    const unsigned* ep = (const unsigned*)(tab + (size_t)gi*256 + c4);
    kp[j][0] = ep[0];
    kp[j][1] = ep[1];
    float dt = tsq - et[j];
    float t0 = __cosf(dt * tw4[0] + tb4[0]);
    float t1 = __cosf(dt * tw4[1] + tb4[1]);
    float t2 = __cosf(dt * tw4[2] + tb4[2]);
    float t3 = __cosf(dt * tw4[3] + tb4[3]);
    kp[j][2] = pk2(t0, t1);
    kp[j][3] = pk2(t2, t3);
    f32x4 e4 = *(const f32x4*)(ef + (size_t)ei[j]*256 + c4);
    kp[j][4] = pk2(e4[0], e4[1]);
    kp[j][5] = pk2(e4[2], e4[3]);
  }

  short* kbb = kbar_l + (size_t)lq * 6144;
  bool zero = (msk == 0x3ffu);

#pragma unroll
  for (int g = 0; g < 2; ++g) {
    __builtin_amdgcn_s_setprio(1);
    // unpack the 4 heads' qk rows for this group (register-only, f32x2 pairs)
    f32x2 qv2[4][6];
#pragma unroll
    for (int hh = 0; hh < 4; ++hh) {
#pragma unroll
      for (int e = 0; e < 6; ++e) qv2[hh][e] = up2(qp[g*4 + hh][e]);
    }
    // scores: j outer (unpack kp[j] once), 4 heads inner; packed-pair FMA + horizontal add
    float s[4][10];
#pragma unroll
    for (int j = 0; j < 10; ++j) {
      f32x2 kt2[6];
#pragma unroll
      for (int e = 0; e < 6; ++e) kt2[e] = up2(kp[j][e]);
#pragma unroll
      for (int hh = 0; hh < 4; ++hh) {
        f32x2 dp = {0.f, 0.f};
#pragma unroll
        for (int e = 0; e < 6; ++e) dp += qv2[hh][e] * kt2[e];
        float d = dp[0] + dp[1];
        d += __shfl_xor(d, 1);  d += __shfl_xor(d, 2);  d += __shfl_xor(d, 4);
        d += __shfl_xor(d, 8);  d += __shfl_xor(d, 16); d += __shfl_xor(d, 32);
        s[hh][j] = ((msk >> j) & 1u) ? -1e9f : d * 0.125f;
      }
    }
    // softmax per head (p kept unnormalized in s; inv folded at write)
    float inv4[4];
#pragma unroll
    for (int hh = 0; hh < 4; ++hh) {
      float mx = s[hh][0];
#pragma unroll
      for (int j = 1; j < 10; ++j) mx = fmaxf(mx, s[hh][j]);
      float sum = 0.f;
#pragma unroll
      for (int j = 0; j < 10; ++j) { s[hh][j] = __expf(s[hh][j] - mx); sum += s[hh][j]; }
      inv4[hh] = 1.f / sum;
    }
    // mixing: j outer (unpack kp[j] once), accumulate 4 heads with packed-pair FMA
    f32x2 ac2[4][6];
#pragma unroll
    for (int hh = 0; hh < 4; ++hh)
#pragma unroll
      for (int e = 0; e < 6; ++e) ac2[hh][e] = (f32x2){0.f, 0.f};
#pragma unroll
    for (int j = 0; j < 10; ++j) {
      f32x2 kt2[6];
#pragma unroll
      for (int e = 0; e < 6; ++e) kt2[e] = up2(kp[j][e]);
#pragma unroll
      for (int hh = 0; hh < 4; ++hh) {
        f32x2 pj2 = {s[hh][j], s[hh][j]};
#pragma unroll
        for (int e = 0; e < 6; ++e) ac2[hh][e] += pj2 * kt2[e];
      }
    }
    __builtin_amdgcn_s_setprio(0);
#pragma unroll
    for (int hh = 0; hh < 4; ++hh) {
      float inv = inv4[hh];
      short4v o0, o1, o2;
#pragma unroll
      for (int e = 0; e < 2; ++e) {
        o0[2*e]   = zero ? (short)0 : f2bf(ac2[hh][e][0] * inv);
        o0[2*e+1] = zero ? (short)0 : f2bf(ac2[hh][e][1] * inv);
        o1[2*e]   = zero ? (short)0 : f2bf(ac2[hh][2+e][0] * inv);
        o1[2*e+1] = zero ? (short)0 : f2bf(ac2[hh][2+e][1] * inv);
        o2[2*e]   = zero ? (short)0 : f2bf(ac2[hh][4+e][0] * inv);
        o2[2*e+1] = zero ? (short)0 : f2bf(ac2[hh][4+e][1] * inv);
      }
      short* kb = kbb + (g*4 + hh)*768;
      *(short4v*)(kb + c4)       = o0;
      *(short4v*)(kb + 256 + c4) = o1;
      *(short4v*)(kb + 512 + c4) = o2;
    }
  }
}

// ---------------- per-head o-projection: out[b][h*64+n] = kbar[b][h]·Wv_h + bv_h ----------------
__global__ __launch_bounds__(256) void gemm_n64_kernel(
    int M, int Kd,
    const short* __restrict__ A, int lda,
    const short* __restrict__ Bt,
    const float* __restrict__ bias,
    short* __restrict__ out, int ldo)
{
  __shared__ short As[128][72];
  __shared__ short Bs[64][72];
  const int bi = blockIdx.x;
  const int h = blockIdx.y;
  const int tid = threadIdx.x;
  const int lane = tid & 63;
  const int wave = tid >> 6;

  const short* Ah = A + (size_t)h * 768;
  const short* Bh = Bt + (size_t)h * 64 * (size_t)Kd;
  const float* biash = bias + h * 64;
  short* outh = out + h * 64;

  f32x4 acc[2][4];
  const f32x4 zv = {0.f, 0.f, 0.f, 0.f};
#pragma unroll
  for (int m = 0; m < 2; ++m)
#pragma unroll
    for (int n = 0; n < 4; ++n) acc[m][n] = zv;

  const size_t arow0 = (size_t)bi * 128;
  for (int kt = 0; kt < Kd; kt += 64) {
#pragma unroll
    for (int it = 0; it < 4; ++it) {
      int chunk = tid + it * 256;
      int row = chunk >> 3;
      int c16 = (chunk & 7) * 8;
      *(short8*)&As[row][c16] = *(const short8*)(Ah + (arow0 + row) * (size_t)lda + kt + c16);
    }
#pragma unroll
    for (int it = 0; it < 2; ++it) {
      int chunk = tid + it * 256;
      int row = chunk >> 3;
      int c16 = (chunk & 7) * 8;
      *(short8*)&Bs[row][c16] = *(const short8*)(Bh + (size_t)row * Kd + kt + c16);
    }
    __syncthreads();
#pragma unroll
    for (int kk = 0; kk < 64; kk += 32) {
      short8 af[2], bfr[4];
#pragma unroll
      for (int m = 0; m < 2; ++m)
        af[m] = *(const short8*)&As[wave*32 + m*16 + (lane & 15)][kk + (lane >> 4) * 8];
#pragma unroll
      for (int n = 0; n < 4; ++n)
        bfr[n] = *(const short8*)&Bs[n*16 + (lane & 15)][kk + (lane >> 4) * 8];
#pragma unroll
      for (int m = 0; m < 2; ++m)
#pragma unroll
        for (int n = 0; n < 4; ++n)
          acc[m][n] = __builtin_amdgcn_mfma_f32_16x16x32_bf16(af[m], bfr[n], acc[m][n], 0, 0, 0);
    }
    __syncthreads();
  }

#pragma unroll
  for (int m = 0; m < 2; ++m) {
#pragma unroll
    for (int r = 0; r < 4; ++r) {
      size_t row = arow0 + wave*32 + m*16 + ((lane >> 4) * 4 + r);
#pragma unroll
      for (int n = 0; n < 4; ++n) {
        int col = n*16 + (lane & 15);
        outh[row * (size_t)ldo + col] = f2bf(acc[m][n][r] + biash[col]);
      }
    }
  }
}

// ---------------- fused MergeLayer: out = relu(A@W1P+b1p) @ W2T + b2 ----------------
template<bool OUTF32>
__global__ __launch_bounds__(256) void w12_kernel(
    const short* __restrict__ A1,      // obuf rows [*][512]
    const short* __restrict__ A2,      // feat rows [*][256] (K 512..767)
    const short* __restrict__ B1,      // W1P [256][768]
    const float* __restrict__ bias1,   // b1p [256]
    const short* __restrict__ B2,      // W2T [256][256]
    const float* __restrict__ bias2,   // b2  [256]
    short* __restrict__ outB, float* __restrict__ outF)
{
  __shared__ short As[128][72];
  __shared__ short Bs[256][72];
  __shared__ short C1[128][280];
  const int tid = threadIdx.x;
  const int lane = tid & 63;
  const int wave = tid >> 6;
  const int wr = (wave >> 1) * 64;
  const int wc = (wave & 1) * 128;
  const size_t arow0 = (size_t)blockIdx.x * 128;

  f32x4 acc[4][8];
  const f32x4 zv = {0.f, 0.f, 0.f, 0.f};
#pragma unroll
  for (int m = 0; m < 4; ++m)
#pragma unroll
    for (int n = 0; n < 8; ++n) acc[m][n] = zv;

  // ---- phase 1: C1 = relu(A @ W1P + b1p), K=768, N=256 ----
  for (int kt = 0; kt < 768; kt += 64) {
#pragma unroll
    for (int it = 0; it < 4; ++it) {
      int chunk = tid + it * 256;
      int row = chunk >> 3;
      int c16 = (chunk & 7) * 8;
      int gk = kt + c16;
      const short* srcA;
      if (gk < 512) srcA = A1 + (arow0 + row) * 512 + gk;
      else          srcA = A2 + (arow0 + row) * 256 + (gk - 512);
      *(short8*)&As[row][c16] = *(const short8*)srcA;
    }
#pragma unroll
    for (int it = 0; it < 8; ++it) {
      int chunk = tid + it * 256;
      int row = chunk >> 3;
      int c16 = (chunk & 7) * 8;
      *(short8*)&Bs[row][c16] = *(const short8*)(B1 + (size_t)row * 768 + kt + c16);
    }
    __syncthreads();
#pragma unroll
    for (int kk = 0; kk < 64; kk += 32) {
      short8 af[4], bfr[8];
#pragma unroll
      for (int m = 0; m < 4; ++m)
        af[m] = *(const short8*)&As[wr + m*16 + (lane & 15)][kk + (lane >> 4) * 8];
#pragma unroll
      for (int n = 0; n < 8; ++n)
        bfr[n] = *(const short8*)&Bs[wc + n*16 + (lane & 15)][kk + (lane >> 4) * 8];
#pragma unroll
      for (int m = 0; m < 4; ++m)
#pragma unroll
        for (int n = 0; n < 8; ++n)
          acc[m][n] = __builtin_amdgcn_mfma_f32_16x16x32_bf16(af[m], bfr[n], acc[m][n], 0, 0, 0);
    }
    __syncthreads();
  }
#pragma unroll
  for (int m = 0; m < 4; ++m) {
#pragma unroll
    for (int r = 0; r < 4; ++r) {
      int row = wr + m*16 + ((lane >> 4) * 4 + r);
#pragma unroll
      for (int n = 0; n < 8; ++n) {
        int col = wc + n*16 + (lane & 15);
        float v = acc[m][n][r] + bias1[col];
        C1[row][col] = f2bf(v > 0.f ? v : 0.f);
        acc[m][n][r] = 0.f;
      }
    }
  }
  __syncthreads();

  // ---- phase 2: out = C1 @ W2T + b2, K=256, N=256 ----
  for (int kt = 0; kt < 256; kt += 64) {
#pragma unroll
    for (int it = 0; it < 8; ++it) {
      int chunk = tid + it * 256;
      int row = chunk >> 3;
      int c16 = (chunk & 7) * 8;
      *(short8*)&Bs[row][c16] = *(const short8*)(B2 + (size_t)row * 256 + kt + c16);
    }
    __syncthreads();
#pragma unroll
    for (int kk = 0; kk < 64; kk += 32) {
      short8 af[4], bfr[8];
#pragma unroll
      for (int m = 0; m < 4; ++m)
        af[m] = *(const short8*)&C1[wr + m*16 + (lane & 15)][kt + kk + (lane >> 4) * 8];
#pragma unroll
      for (int n = 0; n < 8; ++n)
        bfr[n] = *(const short8*)&Bs[wc + n*16 + (lane & 15)][kk + (lane >> 4) * 8];
#pragma unroll
      for (int m = 0; m < 4; ++m)
#pragma unroll
        for (int n = 0; n < 8; ++n)
          acc[m][n] = __builtin_amdgcn_mfma_f32_16x16x32_bf16(af[m], bfr[n], acc[m][n], 0, 0, 0);
    }
    __syncthreads();
  }
#pragma unroll
  for (int m = 0; m < 4; ++m) {
#pragma unroll
    for (int r = 0; r < 4; ++r) {
      size_t row = arow0 + wr + m*16 + ((lane >> 4) * 4 + r);
#pragma unroll
      for (int n = 0; n < 8; ++n) {
        int col = wc + n*16 + (lane & 15);
        float v = acc[m][n][r] + bias2[col];
        if (OUTF32) outF[row * 256 + col] = v;
        else        outB[row * 256 + col] = f2bf(v);
      }
    }
  }
}

// =======================================================================
extern "C" void kernel_launch(void* const* d_in, const int* in_sizes, int n_in,
                              void* d_out, int out_size, void* d_ws, size_t ws_size,
                              hipStream_t stream)
{
  const float* memory   = (const float*)d_in[0];
  const float* node_f   = (const float*)d_in[1];
  const float* edge_f   = (const float*)d_in[2];
  const float* time_w   = (const float*)d_in[3];
  const float* time_b   = (const float*)d_in[4];
  const float* Wq = (const float*)d_in[5];
  const float* bq = (const float*)d_in[6];
  const float* Wk = (const float*)d_in[7];
  const float* bk = (const float*)d_in[8];
  const float* Wv = (const float*)d_in[9];
  const float* bv = (const float*)d_in[10];
  const float* Wo = (const float*)d_in[11];
  const float* bo = (const float*)d_in[12];
  const float* W1 = (const float*)d_in[13];
  const float* b1 = (const float*)d_in[14];
  const float* W2 = (const float*)d_in[15];
  const float* b2 = (const float*)d_in[16];
  const float* timestamps = (const float*)d_in[17];
  const float* et1 = (const float*)d_in[18];
  const float* et2 = (const float*)d_in[19];
  const int* src_nodes  = (const int*)d_in[20];
  const int* neighbors1 = (const int*)d_in[21];
  const int* edge_idx1  = (const int*)d_in[22];
  const int* neighbors2 = (const int*)d_in[23];
  const int* edge_idx2  = (const int*)d_in[24];
  float* out = (float*)d_out;

  char* wsp = (char*)d_ws;
  size_t off = 0;
  auto alloc = [&](size_t bytes) -> void* {
    void* p = wsp + off;
    off += (bytes + 255) & ~(size_t)255;
    return p;
  };
  short* WqT  = (short*)alloc((size_t)2*512*256*2);
  short* WkvT = (short*)alloc((size_t)2*1024*768*2);
  short* WoC  = (short*)alloc((size_t)2*512*512*2);
  short* W1T  = (short*)alloc((size_t)2*256*768*2);
  short* W1P  = (short*)alloc((size_t)2*256*768*2);
  short* W2T  = (short*)alloc((size_t)2*256*256*2);
  short* WkQ  = (short*)alloc((size_t)2*768*512*2);
  float* qconst = (float*)alloc(2*512*4);
  float* bkv    = (float*)alloc(2*1024*4);
  float* b1p    = (float*)alloc(2*256*4);
  float* zbias  = (float*)alloc(512*4);
  short* f_all  = (short*)alloc((size_t)NNODES*256*2);
  short* f_src  = (short*)alloc((size_t)BB*256*2);    // f_src‖f_n1 contiguous
  short* f_n1   = (short*)alloc((size_t)N1R*256*2);
  short* src_l1 = (short*)alloc((size_t)BB*256*2);    // src_l1‖n1_l1 contiguous
  short* n1_l1  = (short*)alloc((size_t)N1R*256*2);
  short* qh     = (short*)alloc((size_t)Q2T*512*2);
  short* obuf   = (short*)alloc((size_t)Q2T*512*2);
  size_t fixed = off;

  // attention intermediates: UNCHUNKED (r8 measured chunking at CB=5632 costs +76 us).
  int CB = 2048;
  {
    const int cands[5] = {22528, 11264, 5632, 2816, 2048};
    for (int c = 0; c < 5; ++c) {
      size_t need = fixed
        + (((size_t)cands[c]*6144*2 + 255) & ~(size_t)255)
        + (((size_t)cands[c]*6144*2 + 255) & ~(size_t)255);
      if (need <= ws_size) { CB = cands[c]; break; }
    }
  }
  short* qkbuf = (short*)alloc((size_t)CB*6144*2);
  short* kbar  = (short*)alloc((size_t)CB*6144*2);

  const int BIG = 1 << 30;
  // ---- fused prep (1 dispatch) ----
  mega_prep_kernel<<<dim3(FALL_BLKS + FEAT_BLKS + PW_BLKS + SM_BLKS + RED_BLKS), dim3(256), 0, stream>>>(
      WqT, WkvT, WoC, W1T, W1P, W2T, WkQ, bkv, zbias, qconst, b1p, f_all,
      f_src, f_n1, src_nodes, neighbors1,
      Wq, Wk, Wv, Wo, W1, W2, bk, bv, bq, bo, b1, time_b, memory, node_f);
  // ---- W1P[:,0:512] for BOTH layers in one dispatch (M=512 spans i; B switches at row 256) ----
  gemm128<false,false><<<dim3(16), dim3(256), 0, stream>>>(
      512, 512, 512, W1T, 768, 512, W1T, 768, WoC, WoC + 262144, 256, zbias, W1P, nullptr, 768);

  // ---- merged calls 1+2 (layer-0 attention over 22528 queries) ----
  gemm128<false,false><<<dim3((Q2T/128)*4), dim3(256), 0, stream>>>(
      Q2T, 512, 256, f_src, 256, 256, f_src, 256, WqT, WqT, BIG, qconst, qh, nullptr, 512);
  for (int b0 = 0; b0 < Q2T; b0 += CB) {
    qk_gemm_kernel<<<dim3((CB/128)*6, 8), dim3(256), 0, stream>>>(
        qh + (size_t)b0*512, WkQ, qkbuf);
    attn_mix10_kernel<1><<<dim3(CB/4), dim3(256), 0, stream>>>(
        qkbuf, f_all, neighbors1, et1, edge_idx1, neighbors2, et2, edge_idx2,
        timestamps, time_w, time_b, edge_f, kbar, b0);
    gemm_n64_kernel<<<dim3(CB/128, 8), dim3(256), 0, stream>>>(
        CB, 768, kbar, 6144, WkvT + 512*768, bkv + 512, obuf + (size_t)b0*512, 512);
  }
  w12_kernel<false><<<dim3(Q2T/128), dim3(256), 0, stream>>>(
      obuf, f_src, W1P, b1p, W2T, b2, src_l1, nullptr);

  // ---- call 3: out = attn(1, src_l1, n1_l1, dt1, ef1, m1) ----
  gemm128<false,false><<<dim3((BB/128)*4), dim3(256), 0, stream>>>(
      BB, 512, 256, src_l1, 256, 256, src_l1, 256, WqT + 512*256, WqT + 512*256, BIG,
      qconst + 512, qh, nullptr, 512);
  qk_gemm_kernel<<<dim3((BB/128)*6, 8), dim3(256), 0, stream>>>(qh, WkQ + 393216, qkbuf);
  attn_mix10_kernel<0><<<dim3(BB/4), dim3(256), 0, stream>>>(
      qkbuf, n1_l1, neighbors1, et1, edge_idx1, neighbors1, et1, edge_idx1,
      timestamps, time_w, time_b, edge_f, kbar, 0);
  gemm_n64_kernel<<<dim3(BB/128, 8), dim3(256), 0, stream>>>(
      BB, 768, kbar, 6144, WkvT + 786432 + 512*768, bkv + 1024 + 512, obuf, 512);
  w12_kernel<true><<<dim3(BB/128), dim3(256), 0, stream>>>(
      obuf, src_l1, W1P + 196608, b1p + 256, W2T + 65536, b2 + 256, nullptr, out);
}